// Round 7
// baseline (161.043 us; speedup 1.0000x reference)
//
#include <hip/hip_runtime.h>
#include <hip/hip_bf16.h>

typedef unsigned short u16;
typedef unsigned int u32;
typedef __bf16 bf16_t;
typedef bf16_t bf16x8 __attribute__((ext_vector_type(8)));
typedef float f32x4 __attribute__((ext_vector_type(4)));

#define NTOT 4096   // H*W*D
#define CCH 128
#define QSCL 0.25503486703f   // log2(e)/sqrt(32)

__device__ __forceinline__ float bf2f(u16 x) {
    return __uint_as_float(((u32)x) << 16);
}
// packed f32x2 -> bf16x2 (v_cvt_pk_bf16_f32), RNE
__device__ __forceinline__ u32 pkbf(float a, float b) {
    __hip_bfloat162 h = __float22bfloat162_rn(make_float2(a, b));
    u32 r; __builtin_memcpy(&r, &h, 4); return r;
}
__device__ __forceinline__ u16 f2bf(float a) {
    return (u16)(pkbf(a, a) & 0xffffu);
}

// ---------------------------------------------------------------------------
// Kernel 1: QKV projections, MFMA, full 128 out-channels per block.
// W converted fp32->bf16 during staging (QSCL folded for p==0).
// grid (64 nt, 3 p, 2 b), block 256.
// Q,K stored [bh][n][d]; V stored [b*128+c][n].
// ---------------------------------------------------------------------------
__global__ __launch_bounds__(256, 4) void proj_kernel(
    const float* __restrict__ xq, const float* __restrict__ xkv,
    const float* __restrict__ Wq, const float* __restrict__ bq_,
    const float* __restrict__ Wk, const float* __restrict__ bk_,
    const float* __restrict__ Wv, const float* __restrict__ bv_,
    u16* __restrict__ Qt, u16* __restrict__ Kt, u16* __restrict__ Vn)
{
    const int nt = blockIdx.x, p = blockIdx.y, b = blockIdx.z;
    const float* X    = (p == 0) ? xq : xkv;
    const float* W    = (p == 0) ? Wq : (p == 1) ? Wk : Wv;
    const float* bias = (p == 0) ? bq_ : (p == 1) ? bk_ : bv_;
    const float scl   = (p == 0) ? QSCL : 1.0f;
    const int n0 = nt * 64;
    const int tid = threadIdx.x;

    __shared__ u16 Xt[64 * 128];        // B tile [n][ci], swizzled
    __shared__ u16 Wl[128 * 136];       // A tile [c][ci], pad stride 136

    // stage X (fp32 -> bf16), 16 ci-chunks of 8 per n
    #pragma unroll
    for (int k = 0; k < 4; ++k) {
        int n = tid & 63;
        int c = (tid >> 6) + k * 4;     // ci-chunk 0..15
        float f[8];
        #pragma unroll
        for (int j = 0; j < 8; ++j)
            f[j] = X[((size_t)(b * CCH) + 8 * c + j) * NTOT + n0 + n];
        uint4 vv = {pkbf(f[0], f[1]), pkbf(f[2], f[3]), pkbf(f[4], f[5]), pkbf(f[6], f[7])};
        *(uint4*)(Xt + n * 128 + ((c ^ (n & 7)) * 8)) = vv;
    }
    // stage W fp32 -> bf16 (scale folded): 128 rows x 16 chunks = 2048
    #pragma unroll
    for (int k = 0; k < 8; ++k) {
        int id = tid + k * 256;         // 0..2047
        int row = id >> 4;              // 0..127
        int off = (id & 15) * 8;        // 0..120
        const float* wsrc = W + (size_t)row * 128 + off;
        float4 f0 = *(const float4*)(wsrc);
        float4 f1 = *(const float4*)(wsrc + 4);
        uint4 vv = {pkbf(f0.x * scl, f0.y * scl), pkbf(f0.z * scl, f0.w * scl),
                    pkbf(f1.x * scl, f1.y * scl), pkbf(f1.z * scl, f1.w * scl)};
        *(uint4*)(Wl + row * 136 + off) = vv;
    }
    __syncthreads();

    const int wave = tid >> 6, lane = tid & 63;
    const int quad = lane >> 4, l16 = lane & 15;
    f32x4 acc[8];
    #pragma unroll
    for (int cf = 0; cf < 8; ++cf) acc[cf] = (f32x4){0.f, 0.f, 0.f, 0.f};

    #pragma unroll
    for (int kk = 0; kk < 4; ++kk) {
        bf16x8 bx = *(const bf16x8*)(Xt + (wave * 16 + l16) * 128 +
                                     (((kk * 4 + quad) ^ (l16 & 7)) * 8));
        #pragma unroll
        for (int cf = 0; cf < 8; ++cf) {
            bf16x8 aw = *(const bf16x8*)(Wl + (cf * 16 + l16) * 136 + kk * 32 + quad * 8);
            acc[cf] = __builtin_amdgcn_mfma_f32_16x16x32_bf16(aw, bx, acc[cf], 0, 0, 0);
        }
    }

    const int n = n0 + wave * 16 + l16;
    #pragma unroll
    for (int cf = 0; cf < 8; ++cf) {
        float4 b4 = *(const float4*)(bias + cf * 16 + quad * 4);
        float v0 = acc[cf][0] + b4.x * scl;
        float v1 = acc[cf][1] + b4.y * scl;
        float v2 = acc[cf][2] + b4.z * scl;
        float v3 = acc[cf][3] + b4.w * scl;
        if (p < 2) {
            const int h = cf >> 1;
            const int d0 = (cf & 1) * 16 + quad * 4;
            u16* dst = (p == 0 ? Qt : Kt) + ((size_t)(b * 4 + h) * NTOT + n) * 32 + d0;
            uint2 vv = {pkbf(v0, v1), pkbf(v2, v3)};
            *(uint2*)dst = vv;
        } else {
            int c = cf * 16 + quad * 4;
            u16* dst = Vn + (size_t)(b * CCH + c) * NTOT + n;
            dst[0 * NTOT] = f2bf(v0); dst[1 * NTOT] = f2bf(v1);
            dst[2 * NTOT] = f2bf(v2); dst[3 * NTOT] = f2bf(v3);
        }
    }
}

// ---------------------------------------------------------------------------
// Kernel 2: flash attention, 64 q per wave (4 groups), 256 q per block.
// K-chunk 512 (kc split 8 -> 1024 blocks, 4/CU). K/V double-buffered LDS;
// P per-wave slot reused per group (wave DS in-order). grid (16 qt, 8 kc, 8 bh).
// ---------------------------------------------------------------------------
__global__ __launch_bounds__(256, 4) void flash_attn_kernel(
    const u16* __restrict__ Qt, const u16* __restrict__ Kt,
    const u16* __restrict__ Vn, u16* __restrict__ pO, float* __restrict__ pL)
{
    const int bh = blockIdx.z, kc = blockIdx.y;
    const int wave = threadIdx.x >> 6, lane = threadIdx.x & 63;
    const int q = lane >> 4, l16 = lane & 15;
    const int q0w = blockIdx.x * 256 + wave * 64;

    const u16* Qbh = Qt + (size_t)bh * NTOT * 32;
    const u16* Kbh = Kt + (size_t)bh * NTOT * 32;
    const u16* Vg  = Vn + ((size_t)((bh >> 2) * CCH + (bh & 3) * 32)) * NTOT;

    __shared__ u16 Kb[2][2048];   // [buf][t(4)][slot 64][8]
    __shared__ u16 Vb[2][2048];   // [buf][mc*2+half][slot 64][8]
    __shared__ u16 Pb[4][1024];   // per-wave P slot (reused per q-group)

    const int kbase = kc * 512;

    bf16x8 bq[4];
    #pragma unroll
    for (int g = 0; g < 4; ++g)
        bq[g] = *(const bf16x8*)(Qbh + (size_t)(q0w + g * 16 + l16) * 32 + q * 8);

    const size_t ksrc = (size_t)(wave * 16 + l16) * 32 + q * 8;
    const size_t vsrc = (size_t)((wave & 1) * 16 + l16) * NTOT + (wave >> 1) * 32 + q * 8;
    const int kv_dst = wave * 512 + lane * 8;

    uint4 kreg = *(const uint4*)(Kbh + (size_t)kbase * 32 + ksrc);
    uint4 vreg = *(const uint4*)(Vg + vsrc + kbase);
    *(uint4*)(&Kb[0][kv_dst]) = kreg;
    *(uint4*)(&Vb[0][kv_dst]) = vreg;
    __syncthreads();

    f32x4 o[4][2];
    #pragma unroll
    for (int g = 0; g < 4; ++g) {
        o[g][0] = (f32x4){0,0,0,0};
        o[g][1] = (f32x4){0,0,0,0};
    }
    const f32x4 zero = {0,0,0,0};
    float lp[4] = {0.f, 0.f, 0.f, 0.f};

    u16* pw = &Pb[wave][0];
    const int pwr = (q >> 1) * 128 + l16 * 8 + (q & 1) * 4;
    const int prd0 = 0 * 512 + lane * 8;
    const int prd1 = 1 * 512 + lane * 8;

    for (int it = 0; it < 8; ++it) {
        const int cur = it & 1;
        if (it < 7) {
            const int m1 = kbase + (it + 1) * 64;
            kreg = *(const uint4*)(Kbh + (size_t)m1 * 32 + ksrc);
            vreg = *(const uint4*)(Vg + vsrc + m1);
        }
        // S for all 4 q-groups (K fragments shared)
        f32x4 s[4][4];
        #pragma unroll
        for (int t = 0; t < 4; ++t) {
            bf16x8 ak = *(const bf16x8*)(&Kb[cur][t * 512 + lane * 8]);
            #pragma unroll
            for (int g = 0; g < 4; ++g)
                s[g][t] = __builtin_amdgcn_mfma_f32_16x16x32_bf16(ak, bq[g], zero, 0, 0, 0);
        }
        // V fragments (shared across groups)
        bf16x8 av00 = *(const bf16x8*)(&Vb[cur][0 * 512 + lane * 8]);
        bf16x8 av01 = *(const bf16x8*)(&Vb[cur][1 * 512 + lane * 8]);
        bf16x8 av10 = *(const bf16x8*)(&Vb[cur][2 * 512 + lane * 8]);
        bf16x8 av11 = *(const bf16x8*)(&Vb[cur][3 * 512 + lane * 8]);
        // per group: exp2 -> P slot -> PV (slot reused; per-wave DS is in-order)
        #pragma unroll
        for (int g = 0; g < 4; ++g) {
            #pragma unroll
            for (int t = 0; t < 4; ++t) {
                float p0 = __builtin_amdgcn_exp2f(s[g][t][0]);
                float p1 = __builtin_amdgcn_exp2f(s[g][t][1]);
                float p2 = __builtin_amdgcn_exp2f(s[g][t][2]);
                float p3 = __builtin_amdgcn_exp2f(s[g][t][3]);
                lp[g] += (p0 + p1) + (p2 + p3);
                uint2 wv = {pkbf(p0, p1), pkbf(p2, p3)};
                *(uint2*)(pw + (t >> 1) * 512 + (t & 1) * 256 + pwr) = wv;
            }
            bf16x8 pb0 = *(const bf16x8*)(pw + prd0);
            bf16x8 pb1 = *(const bf16x8*)(pw + prd1);
            o[g][0] = __builtin_amdgcn_mfma_f32_16x16x32_bf16(av00, pb0, o[g][0], 0, 0, 0);
            o[g][1] = __builtin_amdgcn_mfma_f32_16x16x32_bf16(av01, pb0, o[g][1], 0, 0, 0);
            o[g][0] = __builtin_amdgcn_mfma_f32_16x16x32_bf16(av10, pb1, o[g][0], 0, 0, 0);
            o[g][1] = __builtin_amdgcn_mfma_f32_16x16x32_bf16(av11, pb1, o[g][1], 0, 0, 0);
        }
        if (it < 7) {
            const int nb = (it + 1) & 1;
            *(uint4*)(&Kb[nb][kv_dst]) = kreg;
            *(uint4*)(&Vb[nb][kv_dst]) = vreg;
        }
        __syncthreads();
    }

    #pragma unroll
    for (int g = 0; g < 4; ++g) {
        lp[g] += __shfl_xor(lp[g], 16);
        lp[g] += __shfl_xor(lp[g], 32);
        const size_t ob = ((size_t)(kc * 8 + bh) * NTOT + q0w + g * 16 + l16) * 32 + q * 4;
        uint2 w0 = {pkbf(o[g][0][0], o[g][0][1]), pkbf(o[g][0][2], o[g][0][3])};
        uint2 w1 = {pkbf(o[g][1][0], o[g][1][1]), pkbf(o[g][1][2], o[g][1][3])};
        *(uint2*)(pO + ob)      = w0;
        *(uint2*)(pO + ob + 16) = w1;
        if (q == 0)
            pL[(size_t)(kc * 8 + bh) * NTOT + q0w + g * 16 + l16] = lp[g];
    }
}

// ---------------------------------------------------------------------------
// Kernel 3: fused combine (8 kc) + out-projection + bias + residual -> res,
// plus partial sum/sumsq. Wo converted fp32->bf16 during staging.
// grid (64 nt, 2 ct64, 2 b), block 256.
// ---------------------------------------------------------------------------
__global__ __launch_bounds__(256, 4) void outproj_kernel(
    const float* __restrict__ xq,
    const u16* __restrict__ pO, const float* __restrict__ pL,
    const float* __restrict__ Wo, const float* __restrict__ bo,
    float* __restrict__ res, float* __restrict__ partS, float* __restrict__ partQ)
{
    const int nt = blockIdx.x, ct = blockIdx.y, b = blockIdx.z;
    const int n0 = nt * 64;
    const int tid = threadIdx.x;

    __shared__ u16 Xt[64 * 128];        // combined attn tile [n][ci], swizzled
    __shared__ u16 Wl[64 * 136];        // Wo rows ct*64.., pad stride 136

    #pragma unroll
    for (int k = 0; k < 4; ++k) {
        int cid = tid + k * 256;
        int n = cid >> 4;               // 0..63
        int ch = cid & 15;              // ci-chunk: h = ch>>2, d0 = (ch&3)*8
        int bh = b * 4 + (ch >> 2);
        int d0 = (ch & 3) * 8;
        float l = 0.f;
        float v[8];
        #pragma unroll
        for (int j = 0; j < 8; ++j) v[j] = 0.f;
        #pragma unroll
        for (int kcc = 0; kcc < 8; ++kcc) {
            const size_t nrow = (size_t)(kcc * 8 + bh) * NTOT + n0 + n;
            l += pL[nrow];
            uint4 u = *(const uint4*)(pO + nrow * 32 + d0);
            const u32 uu[4] = {u.x, u.y, u.z, u.w};
            #pragma unroll
            for (int j = 0; j < 4; ++j) {
                v[2 * j]     += bf2f((u16)(uu[j] & 0xffffu));
                v[2 * j + 1] += bf2f((u16)(uu[j] >> 16));
            }
        }
        const float inv = 1.0f / l;
        uint4 vv = {pkbf(v[0] * inv, v[1] * inv), pkbf(v[2] * inv, v[3] * inv),
                    pkbf(v[4] * inv, v[5] * inv), pkbf(v[6] * inv, v[7] * inv)};
        *(uint4*)(Xt + n * 128 + ((ch ^ (n & 7)) * 8)) = vv;
    }
    // stage Wo rows ct*64..ct*64+63 fp32 -> bf16: 1024 chunks
    #pragma unroll
    for (int k = 0; k < 4; ++k) {
        int id = tid + k * 256;         // 0..1023
        int row = id >> 4;              // 0..63
        int off = (id & 15) * 8;        // 0..120
        const float* wsrc = Wo + (size_t)(ct * 64 + row) * 128 + off;
        float4 f0 = *(const float4*)(wsrc);
        float4 f1 = *(const float4*)(wsrc + 4);
        uint4 vv = {pkbf(f0.x, f0.y), pkbf(f0.z, f0.w),
                    pkbf(f1.x, f1.y), pkbf(f1.z, f1.w)};
        *(uint4*)(Wl + row * 136 + off) = vv;
    }
    __syncthreads();

    const int wave = tid >> 6, lane = tid & 63;
    const int quad = lane >> 4, l16 = lane & 15;
    f32x4 acc[4];
    #pragma unroll
    for (int cf = 0; cf < 4; ++cf) acc[cf] = (f32x4){0.f, 0.f, 0.f, 0.f};

    #pragma unroll
    for (int kk = 0; kk < 4; ++kk) {
        bf16x8 bx = *(const bf16x8*)(Xt + (wave * 16 + l16) * 128 +
                                     (((kk * 4 + quad) ^ (l16 & 7)) * 8));
        #pragma unroll
        for (int cf = 0; cf < 4; ++cf) {
            bf16x8 aw = *(const bf16x8*)(Wl + (cf * 16 + l16) * 136 + kk * 32 + quad * 8);
            acc[cf] = __builtin_amdgcn_mfma_f32_16x16x32_bf16(aw, bx, acc[cf], 0, 0, 0);
        }
    }

    const int n = n0 + wave * 16 + l16;
    const int tile = nt * 4 + wave;
    #pragma unroll
    for (int cf = 0; cf < 4; ++cf) {
        float4 b4 = *(const float4*)(bo + ct * 64 + cf * 16 + quad * 4);
        const float bb[4] = {b4.x, b4.y, b4.z, b4.w};
        float sv[4], qv[4];
        #pragma unroll
        for (int r = 0; r < 4; ++r) {
            int c = ct * 64 + cf * 16 + quad * 4 + r;
            float v = acc[cf][r] + bb[r] + xq[(size_t)(b * CCH + c) * NTOT + n];
            res[(size_t)(b * CCH + c) * NTOT + n] = v;
            sv[r] = v;
            qv[r] = v * v;
        }
        #pragma unroll
        for (int off = 1; off < 16; off <<= 1) {
            #pragma unroll
            for (int r = 0; r < 4; ++r) {
                sv[r] += __shfl_xor(sv[r], off);
                qv[r] += __shfl_xor(qv[r], off);
            }
        }
        if (l16 == 0) {
            #pragma unroll
            for (int r = 0; r < 4; ++r) {
                int c = ct * 64 + cf * 16 + quad * 4 + r;
                partS[(size_t)(b * CCH + c) * 256 + tile] = sv[r];
                partQ[(size_t)(b * CCH + c) * 256 + tile] = qv[r];
            }
        }
    }
}

// ---------------------------------------------------------------------------
// Kernel 4: reduce partials, InstanceNorm, fp32 store. grid (128, 2).
// ---------------------------------------------------------------------------
__global__ __launch_bounds__(256) void norm_kernel(
    const float* __restrict__ res, const float* __restrict__ partS,
    const float* __restrict__ partQ, float* __restrict__ out)
{
    const int c = blockIdx.x, b = blockIdx.y;
    const int tid = threadIdx.x;
    const size_t row = (size_t)(b * CCH + c);
    __shared__ float rs[4], rq[4];
    float s = partS[row * 256 + tid];
    float q = partQ[row * 256 + tid];
    #pragma unroll
    for (int off = 1; off < 64; off <<= 1) {
        s += __shfl_xor(s, off);
        q += __shfl_xor(q, off);
    }
    const int wv = tid >> 6, ln = tid & 63;
    if (ln == 0) { rs[wv] = s; rq[wv] = q; }
    __syncthreads();
    float ts = rs[0] + rs[1] + rs[2] + rs[3];
    float tq = rq[0] + rq[1] + rq[2] + rq[3];
    float mu  = ts * (1.0f / 4096.0f);
    float var = tq * (1.0f / 4096.0f) - mu * mu;
    float inv = rsqrtf(var + 1e-5f);
    const size_t base = row * NTOT;
    #pragma unroll
    for (int j = 0; j < 4; ++j) {
        int n = tid * 4 + j * 1024;
        float4 v = *(const float4*)(res + base + n);
        float4 o;
        o.x = (v.x - mu) * inv; o.y = (v.y - mu) * inv;
        o.z = (v.z - mu) * inv; o.w = (v.w - mu) * inv;
        *(float4*)(out + base + n) = o;
    }
}

extern "C" void kernel_launch(void* const* d_in, const int* in_sizes, int n_in,
                              void* d_out, int out_size, void* d_ws, size_t ws_size,
                              hipStream_t stream)
{
    const float* xq  = (const float*)d_in[0];
    const float* xkv = (const float*)d_in[1];
    const float* Wq  = (const float*)d_in[2];
    const float* bq  = (const float*)d_in[3];
    const float* Wk  = (const float*)d_in[4];
    const float* bk  = (const float*)d_in[5];
    const float* Wv  = (const float*)d_in[6];
    const float* bv  = (const float*)d_in[7];
    const float* Wo  = (const float*)d_in[8];
    const float* bo  = (const float*)d_in[9];
    float* out = (float*)d_out;

    char* ws = (char*)d_ws;
    const size_t MB = (size_t)1 << 20;
    u16* Qt = (u16*)(ws + 0 * MB);            // 2 MB [bh][n][d]
    u16* Kt = (u16*)(ws + 2 * MB);            // 2 MB
    u16* Vn = (u16*)(ws + 4 * MB);            // 2 MB [b*128+c][n]
    u16* pO = (u16*)(ws + 6 * MB);            // 16 MB [kc8][bh][n][d]
    float* pL = (float*)(ws + 22 * MB);       // 1 MB [kc8][bh][n]
    float* res   = (float*)(ws + 23 * MB);    // 4 MB
    float* partS = (float*)(ws + 27 * MB);            // 256 KB
    float* partQ = (float*)(ws + 27 * MB + 262144);   // 256 KB

    proj_kernel<<<dim3(64, 3, 2), 256, 0, stream>>>(xq, xkv, Wq, bq, Wk, bk, Wv, bv, Qt, Kt, Vn);
    flash_attn_kernel<<<dim3(16, 8, 8), 256, 0, stream>>>(Qt, Kt, Vn, pO, pL);
    outproj_kernel<<<dim3(64, 2, 2), 256, 0, stream>>>(xq, pO, pL, Wo, bo, res, partS, partQ);
    norm_kernel<<<dim3(128, 2), 256, 0, stream>>>(res, partS, partQ, out);
}

// Round 8
// 127.237 us; speedup vs baseline: 1.2657x; 1.2657x over previous
//
#include <hip/hip_runtime.h>
#include <hip/hip_bf16.h>

typedef unsigned short u16;
typedef unsigned int u32;
typedef __bf16 bf16_t;
typedef bf16_t bf16x8 __attribute__((ext_vector_type(8)));
typedef float f32x4 __attribute__((ext_vector_type(4)));

#define NTOT 4096   // H*W*D
#define CCH 128
#define QSCL 0.25503486703f   // log2(e)/sqrt(32)

__device__ __forceinline__ float bf2f(u16 x) {
    return __uint_as_float(((u32)x) << 16);
}
// packed f32x2 -> bf16x2 (v_cvt_pk_bf16_f32), RNE
__device__ __forceinline__ u32 pkbf(float a, float b) {
    __hip_bfloat162 h = __float22bfloat162_rn(make_float2(a, b));
    u32 r; __builtin_memcpy(&r, &h, 4); return r;
}
__device__ __forceinline__ u16 f2bf(float a) {
    return (u16)(pkbf(a, a) & 0xffffu);
}

// ---------------------------------------------------------------------------
// Kernel 1: QKV projections, MFMA, full 128 out-channels per block.
// W converted fp32->bf16 during staging (QSCL folded for p==0).
// grid (64 nt, 3 p, 2 b), block 256.
// Q,K stored [bh][n][d]; V stored [b*128+c][n].
// ---------------------------------------------------------------------------
__global__ __launch_bounds__(256, 4) void proj_kernel(
    const float* __restrict__ xq, const float* __restrict__ xkv,
    const float* __restrict__ Wq, const float* __restrict__ bq_,
    const float* __restrict__ Wk, const float* __restrict__ bk_,
    const float* __restrict__ Wv, const float* __restrict__ bv_,
    u16* __restrict__ Qt, u16* __restrict__ Kt, u16* __restrict__ Vn)
{
    const int nt = blockIdx.x, p = blockIdx.y, b = blockIdx.z;
    const float* X    = (p == 0) ? xq : xkv;
    const float* W    = (p == 0) ? Wq : (p == 1) ? Wk : Wv;
    const float* bias = (p == 0) ? bq_ : (p == 1) ? bk_ : bv_;
    const float scl   = (p == 0) ? QSCL : 1.0f;
    const int n0 = nt * 64;
    const int tid = threadIdx.x;

    __shared__ u16 Xt[64 * 128];        // B tile [n][ci], swizzled
    __shared__ u16 Wl[128 * 136];       // A tile [c][ci], pad stride 136

    // stage X (fp32 -> bf16), 16 ci-chunks of 8 per n
    #pragma unroll
    for (int k = 0; k < 4; ++k) {
        int n = tid & 63;
        int c = (tid >> 6) + k * 4;     // ci-chunk 0..15
        float f[8];
        #pragma unroll
        for (int j = 0; j < 8; ++j)
            f[j] = X[((size_t)(b * CCH) + 8 * c + j) * NTOT + n0 + n];
        uint4 vv = {pkbf(f[0], f[1]), pkbf(f[2], f[3]), pkbf(f[4], f[5]), pkbf(f[6], f[7])};
        *(uint4*)(Xt + n * 128 + ((c ^ (n & 7)) * 8)) = vv;
    }
    // stage W fp32 -> bf16 (scale folded): 128 rows x 16 chunks = 2048
    #pragma unroll
    for (int k = 0; k < 8; ++k) {
        int id = tid + k * 256;         // 0..2047
        int row = id >> 4;              // 0..127
        int off = (id & 15) * 8;        // 0..120
        const float* wsrc = W + (size_t)row * 128 + off;
        float4 f0 = *(const float4*)(wsrc);
        float4 f1 = *(const float4*)(wsrc + 4);
        uint4 vv = {pkbf(f0.x * scl, f0.y * scl), pkbf(f0.z * scl, f0.w * scl),
                    pkbf(f1.x * scl, f1.y * scl), pkbf(f1.z * scl, f1.w * scl)};
        *(uint4*)(Wl + row * 136 + off) = vv;
    }
    __syncthreads();

    const int wave = tid >> 6, lane = tid & 63;
    const int quad = lane >> 4, l16 = lane & 15;
    f32x4 acc[8];
    #pragma unroll
    for (int cf = 0; cf < 8; ++cf) acc[cf] = (f32x4){0.f, 0.f, 0.f, 0.f};

    #pragma unroll
    for (int kk = 0; kk < 4; ++kk) {
        bf16x8 bx = *(const bf16x8*)(Xt + (wave * 16 + l16) * 128 +
                                     (((kk * 4 + quad) ^ (l16 & 7)) * 8));
        #pragma unroll
        for (int cf = 0; cf < 8; ++cf) {
            bf16x8 aw = *(const bf16x8*)(Wl + (cf * 16 + l16) * 136 + kk * 32 + quad * 8);
            acc[cf] = __builtin_amdgcn_mfma_f32_16x16x32_bf16(aw, bx, acc[cf], 0, 0, 0);
        }
    }

    const int n = n0 + wave * 16 + l16;
    #pragma unroll
    for (int cf = 0; cf < 8; ++cf) {
        float4 b4 = *(const float4*)(bias + cf * 16 + quad * 4);
        float v0 = acc[cf][0] + b4.x * scl;
        float v1 = acc[cf][1] + b4.y * scl;
        float v2 = acc[cf][2] + b4.z * scl;
        float v3 = acc[cf][3] + b4.w * scl;
        if (p < 2) {
            const int h = cf >> 1;
            const int d0 = (cf & 1) * 16 + quad * 4;
            u16* dst = (p == 0 ? Qt : Kt) + ((size_t)(b * 4 + h) * NTOT + n) * 32 + d0;
            uint2 vv = {pkbf(v0, v1), pkbf(v2, v3)};
            *(uint2*)dst = vv;
        } else {
            int c = cf * 16 + quad * 4;
            u16* dst = Vn + (size_t)(b * CCH + c) * NTOT + n;
            dst[0 * NTOT] = f2bf(v0); dst[1 * NTOT] = f2bf(v1);
            dst[2 * NTOT] = f2bf(v2); dst[3 * NTOT] = f2bf(v3);
        }
    }
}

// ---------------------------------------------------------------------------
// Kernel 2: flash attention, 64 q per wave (4 groups), 256 q per block.
// K-chunk 512 (kc split 8 -> 1024 blocks, 4/CU). K/V double-buffered LDS;
// P per-wave slot reused per group (wave DS in-order). grid (16 qt, 8 kc, 8 bh).
// launch_bounds (256,2): (256,4) capped VGPR at 64 -> scratch spill -> 155 MB
// HBM write traffic (r7 regression). 92 VGPR needs the 256-cap.
// ---------------------------------------------------------------------------
__global__ __launch_bounds__(256, 2) void flash_attn_kernel(
    const u16* __restrict__ Qt, const u16* __restrict__ Kt,
    const u16* __restrict__ Vn, u16* __restrict__ pO, float* __restrict__ pL)
{
    const int bh = blockIdx.z, kc = blockIdx.y;
    const int wave = threadIdx.x >> 6, lane = threadIdx.x & 63;
    const int q = lane >> 4, l16 = lane & 15;
    const int q0w = blockIdx.x * 256 + wave * 64;

    const u16* Qbh = Qt + (size_t)bh * NTOT * 32;
    const u16* Kbh = Kt + (size_t)bh * NTOT * 32;
    const u16* Vg  = Vn + ((size_t)((bh >> 2) * CCH + (bh & 3) * 32)) * NTOT;

    __shared__ u16 Kb[2][2048];   // [buf][t(4)][slot 64][8]
    __shared__ u16 Vb[2][2048];   // [buf][mc*2+half][slot 64][8]
    __shared__ u16 Pb[4][1024];   // per-wave P slot (reused per q-group)

    const int kbase = kc * 512;

    bf16x8 bq[4];
    #pragma unroll
    for (int g = 0; g < 4; ++g)
        bq[g] = *(const bf16x8*)(Qbh + (size_t)(q0w + g * 16 + l16) * 32 + q * 8);

    const size_t ksrc = (size_t)(wave * 16 + l16) * 32 + q * 8;
    const size_t vsrc = (size_t)((wave & 1) * 16 + l16) * NTOT + (wave >> 1) * 32 + q * 8;
    const int kv_dst = wave * 512 + lane * 8;

    uint4 kreg = *(const uint4*)(Kbh + (size_t)kbase * 32 + ksrc);
    uint4 vreg = *(const uint4*)(Vg + vsrc + kbase);
    *(uint4*)(&Kb[0][kv_dst]) = kreg;
    *(uint4*)(&Vb[0][kv_dst]) = vreg;
    __syncthreads();

    f32x4 o[4][2];
    #pragma unroll
    for (int g = 0; g < 4; ++g) {
        o[g][0] = (f32x4){0,0,0,0};
        o[g][1] = (f32x4){0,0,0,0};
    }
    const f32x4 zero = {0,0,0,0};
    float lp[4] = {0.f, 0.f, 0.f, 0.f};

    u16* pw = &Pb[wave][0];
    const int pwr = (q >> 1) * 128 + l16 * 8 + (q & 1) * 4;
    const int prd0 = 0 * 512 + lane * 8;
    const int prd1 = 1 * 512 + lane * 8;

    for (int it = 0; it < 8; ++it) {
        const int cur = it & 1;
        if (it < 7) {
            const int m1 = kbase + (it + 1) * 64;
            kreg = *(const uint4*)(Kbh + (size_t)m1 * 32 + ksrc);
            vreg = *(const uint4*)(Vg + vsrc + m1);
        }
        // S for all 4 q-groups (K fragments shared)
        f32x4 s[4][4];
        #pragma unroll
        for (int t = 0; t < 4; ++t) {
            bf16x8 ak = *(const bf16x8*)(&Kb[cur][t * 512 + lane * 8]);
            #pragma unroll
            for (int g = 0; g < 4; ++g)
                s[g][t] = __builtin_amdgcn_mfma_f32_16x16x32_bf16(ak, bq[g], zero, 0, 0, 0);
        }
        // V fragments (shared across groups)
        bf16x8 av00 = *(const bf16x8*)(&Vb[cur][0 * 512 + lane * 8]);
        bf16x8 av01 = *(const bf16x8*)(&Vb[cur][1 * 512 + lane * 8]);
        bf16x8 av10 = *(const bf16x8*)(&Vb[cur][2 * 512 + lane * 8]);
        bf16x8 av11 = *(const bf16x8*)(&Vb[cur][3 * 512 + lane * 8]);
        // per group: exp2 -> P slot -> PV (slot reused; per-wave DS is in-order)
        #pragma unroll
        for (int g = 0; g < 4; ++g) {
            #pragma unroll
            for (int t = 0; t < 4; ++t) {
                float p0 = __builtin_amdgcn_exp2f(s[g][t][0]);
                float p1 = __builtin_amdgcn_exp2f(s[g][t][1]);
                float p2 = __builtin_amdgcn_exp2f(s[g][t][2]);
                float p3 = __builtin_amdgcn_exp2f(s[g][t][3]);
                lp[g] += (p0 + p1) + (p2 + p3);
                uint2 wv = {pkbf(p0, p1), pkbf(p2, p3)};
                *(uint2*)(pw + (t >> 1) * 512 + (t & 1) * 256 + pwr) = wv;
            }
            bf16x8 pb0 = *(const bf16x8*)(pw + prd0);
            bf16x8 pb1 = *(const bf16x8*)(pw + prd1);
            o[g][0] = __builtin_amdgcn_mfma_f32_16x16x32_bf16(av00, pb0, o[g][0], 0, 0, 0);
            o[g][1] = __builtin_amdgcn_mfma_f32_16x16x32_bf16(av01, pb0, o[g][1], 0, 0, 0);
            o[g][0] = __builtin_amdgcn_mfma_f32_16x16x32_bf16(av10, pb1, o[g][0], 0, 0, 0);
            o[g][1] = __builtin_amdgcn_mfma_f32_16x16x32_bf16(av11, pb1, o[g][1], 0, 0, 0);
        }
        if (it < 7) {
            const int nb = (it + 1) & 1;
            *(uint4*)(&Kb[nb][kv_dst]) = kreg;
            *(uint4*)(&Vb[nb][kv_dst]) = vreg;
        }
        __syncthreads();
    }

    #pragma unroll
    for (int g = 0; g < 4; ++g) {
        lp[g] += __shfl_xor(lp[g], 16);
        lp[g] += __shfl_xor(lp[g], 32);
        const size_t ob = ((size_t)(kc * 8 + bh) * NTOT + q0w + g * 16 + l16) * 32 + q * 4;
        uint2 w0 = {pkbf(o[g][0][0], o[g][0][1]), pkbf(o[g][0][2], o[g][0][3])};
        uint2 w1 = {pkbf(o[g][1][0], o[g][1][1]), pkbf(o[g][1][2], o[g][1][3])};
        *(uint2*)(pO + ob)      = w0;
        *(uint2*)(pO + ob + 16) = w1;
        if (q == 0)
            pL[(size_t)(kc * 8 + bh) * NTOT + q0w + g * 16 + l16] = lp[g];
    }
}

// ---------------------------------------------------------------------------
// Kernel 3: fused combine (8 kc) + out-projection + bias + residual -> res,
// plus partial sum/sumsq. Wo converted fp32->bf16 during staging.
// grid (64 nt, 2 ct64, 2 b), block 256.
// ---------------------------------------------------------------------------
__global__ __launch_bounds__(256, 4) void outproj_kernel(
    const float* __restrict__ xq,
    const u16* __restrict__ pO, const float* __restrict__ pL,
    const float* __restrict__ Wo, const float* __restrict__ bo,
    float* __restrict__ res, float* __restrict__ partS, float* __restrict__ partQ)
{
    const int nt = blockIdx.x, ct = blockIdx.y, b = blockIdx.z;
    const int n0 = nt * 64;
    const int tid = threadIdx.x;

    __shared__ u16 Xt[64 * 128];        // combined attn tile [n][ci], swizzled
    __shared__ u16 Wl[64 * 136];        // Wo rows ct*64.., pad stride 136

    #pragma unroll
    for (int k = 0; k < 4; ++k) {
        int cid = tid + k * 256;
        int n = cid >> 4;               // 0..63
        int ch = cid & 15;              // ci-chunk: h = ch>>2, d0 = (ch&3)*8
        int bh = b * 4 + (ch >> 2);
        int d0 = (ch & 3) * 8;
        float l = 0.f;
        float v[8];
        #pragma unroll
        for (int j = 0; j < 8; ++j) v[j] = 0.f;
        #pragma unroll
        for (int kcc = 0; kcc < 8; ++kcc) {
            const size_t nrow = (size_t)(kcc * 8 + bh) * NTOT + n0 + n;
            l += pL[nrow];
            uint4 u = *(const uint4*)(pO + nrow * 32 + d0);
            const u32 uu[4] = {u.x, u.y, u.z, u.w};
            #pragma unroll
            for (int j = 0; j < 4; ++j) {
                v[2 * j]     += bf2f((u16)(uu[j] & 0xffffu));
                v[2 * j + 1] += bf2f((u16)(uu[j] >> 16));
            }
        }
        const float inv = 1.0f / l;
        uint4 vv = {pkbf(v[0] * inv, v[1] * inv), pkbf(v[2] * inv, v[3] * inv),
                    pkbf(v[4] * inv, v[5] * inv), pkbf(v[6] * inv, v[7] * inv)};
        *(uint4*)(Xt + n * 128 + ((ch ^ (n & 7)) * 8)) = vv;
    }
    // stage Wo rows ct*64..ct*64+63 fp32 -> bf16: 1024 chunks
    #pragma unroll
    for (int k = 0; k < 4; ++k) {
        int id = tid + k * 256;         // 0..1023
        int row = id >> 4;              // 0..63
        int off = (id & 15) * 8;        // 0..120
        const float* wsrc = Wo + (size_t)(ct * 64 + row) * 128 + off;
        float4 f0 = *(const float4*)(wsrc);
        float4 f1 = *(const float4*)(wsrc + 4);
        uint4 vv = {pkbf(f0.x, f0.y), pkbf(f0.z, f0.w),
                    pkbf(f1.x, f1.y), pkbf(f1.z, f1.w)};
        *(uint4*)(Wl + row * 136 + off) = vv;
    }
    __syncthreads();

    const int wave = tid >> 6, lane = tid & 63;
    const int quad = lane >> 4, l16 = lane & 15;
    f32x4 acc[4];
    #pragma unroll
    for (int cf = 0; cf < 4; ++cf) acc[cf] = (f32x4){0.f, 0.f, 0.f, 0.f};

    #pragma unroll
    for (int kk = 0; kk < 4; ++kk) {
        bf16x8 bx = *(const bf16x8*)(Xt + (wave * 16 + l16) * 128 +
                                     (((kk * 4 + quad) ^ (l16 & 7)) * 8));
        #pragma unroll
        for (int cf = 0; cf < 4; ++cf) {
            bf16x8 aw = *(const bf16x8*)(Wl + (cf * 16 + l16) * 136 + kk * 32 + quad * 8);
            acc[cf] = __builtin_amdgcn_mfma_f32_16x16x32_bf16(aw, bx, acc[cf], 0, 0, 0);
        }
    }

    const int n = n0 + wave * 16 + l16;
    const int tile = nt * 4 + wave;
    #pragma unroll
    for (int cf = 0; cf < 4; ++cf) {
        float4 b4 = *(const float4*)(bo + ct * 64 + cf * 16 + quad * 4);
        const float bb[4] = {b4.x, b4.y, b4.z, b4.w};
        float sv[4], qv[4];
        #pragma unroll
        for (int r = 0; r < 4; ++r) {
            int c = ct * 64 + cf * 16 + quad * 4 + r;
            float v = acc[cf][r] + bb[r] + xq[(size_t)(b * CCH + c) * NTOT + n];
            res[(size_t)(b * CCH + c) * NTOT + n] = v;
            sv[r] = v;
            qv[r] = v * v;
        }
        #pragma unroll
        for (int off = 1; off < 16; off <<= 1) {
            #pragma unroll
            for (int r = 0; r < 4; ++r) {
                sv[r] += __shfl_xor(sv[r], off);
                qv[r] += __shfl_xor(qv[r], off);
            }
        }
        if (l16 == 0) {
            #pragma unroll
            for (int r = 0; r < 4; ++r) {
                int c = ct * 64 + cf * 16 + quad * 4 + r;
                partS[(size_t)(b * CCH + c) * 256 + tile] = sv[r];
                partQ[(size_t)(b * CCH + c) * 256 + tile] = qv[r];
            }
        }
    }
}

// ---------------------------------------------------------------------------
// Kernel 4: reduce partials, InstanceNorm, fp32 store. grid (128, 2).
// ---------------------------------------------------------------------------
__global__ __launch_bounds__(256) void norm_kernel(
    const float* __restrict__ res, const float* __restrict__ partS,
    const float* __restrict__ partQ, float* __restrict__ out)
{
    const int c = blockIdx.x, b = blockIdx.y;
    const int tid = threadIdx.x;
    const size_t row = (size_t)(b * CCH + c);
    __shared__ float rs[4], rq[4];
    float s = partS[row * 256 + tid];
    float q = partQ[row * 256 + tid];
    #pragma unroll
    for (int off = 1; off < 64; off <<= 1) {
        s += __shfl_xor(s, off);
        q += __shfl_xor(q, off);
    }
    const int wv = tid >> 6, ln = tid & 63;
    if (ln == 0) { rs[wv] = s; rq[wv] = q; }
    __syncthreads();
    float ts = rs[0] + rs[1] + rs[2] + rs[3];
    float tq = rq[0] + rq[1] + rq[2] + rq[3];
    float mu  = ts * (1.0f / 4096.0f);
    float var = tq * (1.0f / 4096.0f) - mu * mu;
    float inv = rsqrtf(var + 1e-5f);
    const size_t base = row * NTOT;
    #pragma unroll
    for (int j = 0; j < 4; ++j) {
        int n = tid * 4 + j * 1024;
        float4 v = *(const float4*)(res + base + n);
        float4 o;
        o.x = (v.x - mu) * inv; o.y = (v.y - mu) * inv;
        o.z = (v.z - mu) * inv; o.w = (v.w - mu) * inv;
        *(float4*)(out + base + n) = o;
    }
}

extern "C" void kernel_launch(void* const* d_in, const int* in_sizes, int n_in,
                              void* d_out, int out_size, void* d_ws, size_t ws_size,
                              hipStream_t stream)
{
    const float* xq  = (const float*)d_in[0];
    const float* xkv = (const float*)d_in[1];
    const float* Wq  = (const float*)d_in[2];
    const float* bq  = (const float*)d_in[3];
    const float* Wk  = (const float*)d_in[4];
    const float* bk  = (const float*)d_in[5];
    const float* Wv  = (const float*)d_in[6];
    const float* bv  = (const float*)d_in[7];
    const float* Wo  = (const float*)d_in[8];
    const float* bo  = (const float*)d_in[9];
    float* out = (float*)d_out;

    char* ws = (char*)d_ws;
    const size_t MB = (size_t)1 << 20;
    u16* Qt = (u16*)(ws + 0 * MB);            // 2 MB [bh][n][d]
    u16* Kt = (u16*)(ws + 2 * MB);            // 2 MB
    u16* Vn = (u16*)(ws + 4 * MB);            // 2 MB [b*128+c][n]
    u16* pO = (u16*)(ws + 6 * MB);            // 16 MB [kc8][bh][n][d]
    float* pL = (float*)(ws + 22 * MB);       // 1 MB [kc8][bh][n]
    float* res   = (float*)(ws + 23 * MB);    // 4 MB
    float* partS = (float*)(ws + 27 * MB);            // 256 KB
    float* partQ = (float*)(ws + 27 * MB + 262144);   // 256 KB

    proj_kernel<<<dim3(64, 3, 2), 256, 0, stream>>>(xq, xkv, Wq, bq, Wk, bk, Wv, bv, Qt, Kt, Vn);
    flash_attn_kernel<<<dim3(16, 8, 8), 256, 0, stream>>>(Qt, Kt, Vn, pO, pL);
    outproj_kernel<<<dim3(64, 2, 2), 256, 0, stream>>>(xq, pO, pL, Wo, bo, res, partS, partQ);
    norm_kernel<<<dim3(128, 2), 256, 0, stream>>>(res, partS, partQ, out);
}